// Round 5
// baseline (1120.967 us; speedup 1.0000x reference)
//
#include <hip/hip_runtime.h>
#include <hip/hip_bf16.h>

#define SEQ   2048
#define BATCH 256
#define HDIM  64
#define GDIM  256   // 4*H

typedef __attribute__((ext_vector_type(4))) float f32x4;

// Pure-VALU fp32 LSTM: one workgroup per batch element, 4 waves.
// Thread (w, l): gate part p = l>>4 (0=i,1=f,2=g~,3=o), unit u = 16w + (l&15),
// gate column g = 64p + u. W_hh column in registers (64 fp32), h in LDS fp32.
// The 4 gate pre-activations of unit u live in one wave -> __shfl gather.
// All outputs stored as FP32 (reference output dtype is float32).
__global__ __launch_bounds__(256) void lstm_valu(
    const float* __restrict__ xin,   // [S,B,2] fp32
    const float* __restrict__ Wih,   // [2,256] fp32
    const float* __restrict__ Whh,   // [64,256] fp32
    const float* __restrict__ bih,   // [256] fp32
    const float* __restrict__ bhh,   // [256] fp32
    float* __restrict__ out)         // fp32: hidden_seq [S,B,64] | h [B,64] | c [B,64]
{
    const int b   = blockIdx.x;
    const int tid = threadIdx.x;
    const int w   = tid >> 6;    // wave 0..3
    const int l   = tid & 63;    // lane
    const int p   = l >> 4;      // gate part: 0=i, 1=f, 2=g~, 3=o
    const int lc  = l & 15;
    const int u   = 16 * w + lc; // hidden unit
    const int g   = 64 * p + u;  // gate column in [0,256)

    __shared__ __align__(16) float hvec[2][HDIM];  // fp32 h, double buffered
    __shared__ float2 xf[SEQ];                     // staged x pairs (fp32)

    // ---- stage x for this batch column ----
    const float2* x2 = reinterpret_cast<const float2*>(xin);
    #pragma unroll
    for (int r = 0; r < SEQ / 256; ++r) {
        int s = r * 256 + tid;
        xf[s] = x2[(size_t)s * BATCH + b];
    }

    // ---- weights into registers: this thread's W_hh column ----
    float wcol[HDIM];
    #pragma unroll
    for (int k = 0; k < HDIM; ++k) wcol[k] = Whh[k * GDIM + g];
    const float wx0  = Wih[0 * GDIM + g];
    const float wx1  = Wih[1 * GDIM + g];
    const float bias = bih[g] + bhh[g];

    if (tid < HDIM) { hvec[0][tid] = 0.0f; hvec[1][tid] = 0.0f; }
    float c_state = 0.0f;
    float hval    = 0.0f;
    __syncthreads();

    const float L2E = 1.44269504088896340736f;

    for (int s = 0; s < SEQ; ++s) {
        const int buf = s & 1;
        const float2 xv = xf[s];

        // pre-activation: bias + x@Wih + h@Whh (4 independent chains for ILP)
        float a0 = bias + wx0 * xv.x;
        float a1 = wx1 * xv.y;
        float a2 = 0.0f;
        float a3 = 0.0f;
        const f32x4* hv = reinterpret_cast<const f32x4*>(&hvec[buf][0]);
        #pragma unroll
        for (int q = 0; q < HDIM / 4; q += 4) {
            f32x4 h0 = hv[q + 0], h1 = hv[q + 1], h2 = hv[q + 2], h3 = hv[q + 3];
            #pragma unroll
            for (int e = 0; e < 4; ++e) {
                a0 += h0[e] * wcol[4 * (q + 0) + e];
                a1 += h1[e] * wcol[4 * (q + 1) + e];
                a2 += h2[e] * wcol[4 * (q + 2) + e];
                a3 += h3[e] * wcol[4 * (q + 3) + e];
            }
        }
        const float pa = (a0 + a1) + (a2 + a3);

        // activation: sigmoid for p!=2, tanh for p==2 via tanh(x)=2*sigmoid(2x)-1
        const float arg = (p == 2) ? 2.0f * pa : pa;
        const float sg  = __builtin_amdgcn_rcpf(1.0f + __builtin_amdgcn_exp2f(-L2E * arg));
        const float act = (p == 2) ? 2.0f * sg - 1.0f : sg;

        // gather i,f,g~,o of unit u (all within this wave)
        const float iv = __shfl(act, lc +  0, 64);
        const float fv = __shfl(act, lc + 16, 64);
        const float gv = __shfl(act, lc + 32, 64);
        const float ov = __shfl(act, lc + 48, 64);

        c_state = fv * c_state + iv * gv;
        const float tc = 2.0f * __builtin_amdgcn_rcpf(1.0f + __builtin_amdgcn_exp2f(-2.0f * L2E * c_state)) - 1.0f;
        hval = ov * tc;

        if (l < 16) {
            hvec[buf ^ 1][u] = hval;  // feed next step (fp32)
            // direct fp32 store: out[s][b][u] (256B contiguous per block-step)
            out[(size_t)s * (BATCH * HDIM) + (size_t)b * HDIM + u] = hval;
        }
        __syncthreads();
    }

    // final h, c (fp32)
    if (l < 16) {
        const size_t HO = (size_t)SEQ * BATCH * HDIM;
        out[HO + (size_t)b * HDIM + u] = hval;
        out[HO + (size_t)BATCH * HDIM + (size_t)b * HDIM + u] = c_state;
    }
}

extern "C" void kernel_launch(void* const* d_in, const int* in_sizes, int n_in,
                              void* d_out, int out_size, void* d_ws, size_t ws_size,
                              hipStream_t stream) {
    const float* xin = (const float*)d_in[0];
    const float* Wih = (const float*)d_in[1];
    const float* Whh = (const float*)d_in[2];
    const float* bih = (const float*)d_in[3];
    const float* bhh = (const float*)d_in[4];
    float* out = (float*)d_out;

    lstm_valu<<<BATCH, 256, 0, stream>>>(xin, Wih, Whh, bih, bhh, out);
}

// Round 6
// 722.201 us; speedup vs baseline: 1.5522x; 1.5522x over previous
//
#include <hip/hip_runtime.h>

#define SEQ   2048
#define BATCH 256
#define HDIM  64
#define GDIM  256   // 4*H

typedef __attribute__((ext_vector_type(4))) float f32x4;

static __device__ __forceinline__ float quad_xor1(float v) {
    return __builtin_bit_cast(float,
        __builtin_amdgcn_mov_dpp(__builtin_bit_cast(int, v), 0xB1, 0xF, 0xF, true));
}
static __device__ __forceinline__ float quad_xor2(float v) {
    return __builtin_bit_cast(float,
        __builtin_amdgcn_mov_dpp(__builtin_bit_cast(int, v), 0x4E, 0xF, 0xF, true));
}

// fp32 VALU LSTM, quad-split matvec. One workgroup per batch element, 4 waves.
// Lane (w,l): p=l&3 is a 16-wide k-slice, q=l>>2, unit u=16w+q.
// Each lane computes partial dots of ALL FOUR gates of unit u over its k-slice,
// quad-butterfly (DPP) reduces -> every lane holds i,f,g,o pre-acts -> fully
// in-lane activations/c/h. Barrier = raw lgkmcnt(0)+s_barrier (no vmcnt drain,
// so per-step global stores stay off the critical chain).
__global__ __launch_bounds__(256) void lstm_valu2(
    const float* __restrict__ xin,   // [S,B,2]
    const float* __restrict__ Wih,   // [2,256]
    const float* __restrict__ Whh,   // [64,256]
    const float* __restrict__ bih,   // [256]
    const float* __restrict__ bhh,   // [256]
    float* __restrict__ out)         // fp32: hidden_seq [S,B,64] | h [B,64] | c [B,64]
{
    const int b   = blockIdx.x;
    const int tid = threadIdx.x;
    const int w   = tid >> 6;    // wave 0..3
    const int l   = tid & 63;    // lane
    const int p   = l & 3;       // k-slice 0..3  (k in [16p, 16p+16))
    const int q   = l >> 2;      // unit-within-wave 0..15
    const int u   = 16 * w + q;  // hidden unit

    __shared__ __align__(16) float hvec[2][HDIM];  // fp32 h, double buffered
    __shared__ float2 xf[SEQ];                     // staged x pairs

    // ---- stage x for this batch column ----
    const float2* x2 = reinterpret_cast<const float2*>(xin);
    #pragma unroll
    for (int r = 0; r < SEQ / 256; ++r) {
        int s = r * 256 + tid;
        xf[s] = x2[(size_t)s * BATCH + b];
    }

    // ---- weights: wcol[t][e] = Whh[16p+e][64t+u]  (t: 0=i,1=f,2=g,3=o) ----
    float wcol[4][16];
    #pragma unroll
    for (int t = 0; t < 4; ++t)
        #pragma unroll
        for (int e = 0; e < 16; ++e)
            wcol[t][e] = Whh[(16 * p + e) * GDIM + (64 * t + u)];
    float wx0[4], wx1[4], bias[4];
    #pragma unroll
    for (int t = 0; t < 4; ++t) {
        wx0[t]  = Wih[0 * GDIM + 64 * t + u];
        wx1[t]  = Wih[1 * GDIM + 64 * t + u];
        bias[t] = bih[64 * t + u] + bhh[64 * t + u];
    }

    if (tid < HDIM) { hvec[0][tid] = 0.0f; hvec[1][tid] = 0.0f; }
    float c_state = 0.0f, hval = 0.0f;
    __syncthreads();

    const float L2E = 1.44269504088896340736f;

    #pragma unroll 2
    for (int s = 0; s < SEQ; ++s) {
        const int buf = s & 1;
        const float2 xv = xf[s];

        // x + bias terms (independent of h; overlaps the ds_reads)
        float xb[4];
        #pragma unroll
        for (int t = 0; t < 4; ++t)
            xb[t] = bias[t] + wx0[t] * xv.x + wx1[t] * xv.y;

        // h k-slice [16p, 16p+16)
        const f32x4* hv = reinterpret_cast<const f32x4*>(&hvec[buf][16 * p]);
        const f32x4 h0 = hv[0], h1 = hv[1], h2 = hv[2], h3 = hv[3];

        // partial dots: 4 gates x 16 k  (4 independent chains each)
        float acc[4];
        #pragma unroll
        for (int t = 0; t < 4; ++t) {
            float a0 = 0.f, a1 = 0.f, a2 = 0.f, a3 = 0.f;
            #pragma unroll
            for (int e = 0; e < 4; ++e) {
                a0 += h0[e] * wcol[t][e];
                a1 += h1[e] * wcol[t][4 + e];
                a2 += h2[e] * wcol[t][8 + e];
                a3 += h3[e] * wcol[t][12 + e];
            }
            acc[t] = (a0 + a1) + (a2 + a3);
        }

        // quad butterfly: every lane gets full 64-k sums for all 4 gates
        #pragma unroll
        for (int t = 0; t < 4; ++t) {
            acc[t] += quad_xor1(acc[t]);
            acc[t] += quad_xor2(acc[t]);
            acc[t] += xb[t];
        }

        // activations (in-lane): i,f,o sigmoid; g tanh
        const float iv = __builtin_amdgcn_rcpf(1.0f + __builtin_amdgcn_exp2f(-L2E * acc[0]));
        const float fv = __builtin_amdgcn_rcpf(1.0f + __builtin_amdgcn_exp2f(-L2E * acc[1]));
        const float gv = 2.0f * __builtin_amdgcn_rcpf(1.0f + __builtin_amdgcn_exp2f(-2.0f * L2E * acc[2])) - 1.0f;
        const float ov = __builtin_amdgcn_rcpf(1.0f + __builtin_amdgcn_exp2f(-L2E * acc[3]));

        c_state = fv * c_state + iv * gv;
        const float tc = 2.0f * __builtin_amdgcn_rcpf(1.0f + __builtin_amdgcn_exp2f(-2.0f * L2E * c_state)) - 1.0f;
        hval = ov * tc;

        if (p == 0) {
            hvec[buf ^ 1][u] = hval;   // feed next step
            out[(size_t)s * (BATCH * HDIM) + (size_t)b * HDIM + u] = hval;  // fire-and-forget
        }

        // LDS-only barrier: order h exchange WITHOUT draining global stores
        __builtin_amdgcn_sched_barrier(0);
        asm volatile("s_waitcnt lgkmcnt(0)\n\ts_barrier" ::: "memory");
        __builtin_amdgcn_sched_barrier(0);
    }

    // final h, c
    if (p == 0) {
        const size_t HO = (size_t)SEQ * BATCH * HDIM;
        out[HO + (size_t)b * HDIM + u] = hval;
        out[HO + (size_t)BATCH * HDIM + (size_t)b * HDIM + u] = c_state;
    }
}

extern "C" void kernel_launch(void* const* d_in, const int* in_sizes, int n_in,
                              void* d_out, int out_size, void* d_ws, size_t ws_size,
                              hipStream_t stream) {
    const float* xin = (const float*)d_in[0];
    const float* Wih = (const float*)d_in[1];
    const float* Whh = (const float*)d_in[2];
    const float* bih = (const float*)d_in[3];
    const float* bhh = (const float*)d_in[4];
    float* out = (float*)d_out;

    lstm_valu2<<<BATCH, 256, 0, stream>>>(xin, Wih, Whh, bih, bhh, out);
}